// Round 1
// baseline (124.030 us; speedup 1.0000x reference)
//
#include <hip/hip_runtime.h>
#include <math.h>

#define BSZ 4
#define LEN_M 256
#define LEN_E 512
#define HDIM 512
#define VOCAB 32000

#define TILE 64
#define LPAD 68   // 64 + 4 pad: float4-aligned, row stride 272 words -> 2-way bank alias (free)

// ---------------- C[M,N] = scale * A[M,K] @ B[K,N], all row-major -------------
__global__ __launch_bounds__(256) void gemm_nn(const float* __restrict__ A,
                                               const float* __restrict__ B,
                                               float* __restrict__ C,
                                               int M, int N, int K, float scale) {
    __shared__ float As[TILE][LPAD];   // [m][kk]
    __shared__ float Bs[TILE][LPAD];   // [kk][n]
    const int t  = threadIdx.x;
    const int tx = t & 15, ty = t >> 4;
    const int m0 = blockIdx.y * TILE, n0 = blockIdx.x * TILE;
    const int lm = t >> 4;            // row within a 16-row staging pass
    const int lk = (t & 15) * 4;      // float4 column offset

    float acc[4][4] = {};

    for (int k0 = 0; k0 < K; k0 += TILE) {
#pragma unroll
        for (int r = 0; r < 4; ++r) {
            const int row = lm + r * 16;
            *(float4*)&As[row][lk] = *(const float4*)&A[(size_t)(m0 + row) * K + k0 + lk];
            *(float4*)&Bs[row][lk] = *(const float4*)&B[(size_t)(k0 + row) * N + n0 + lk];
        }
        __syncthreads();
#pragma unroll
        for (int kk4 = 0; kk4 < 16; ++kk4) {
            float4 a[4], bb[4];
#pragma unroll
            for (int i = 0; i < 4; ++i) a[i]  = *(const float4*)&As[ty * 4 + i][kk4 * 4];
#pragma unroll
            for (int j = 0; j < 4; ++j) bb[j] = *(const float4*)&Bs[kk4 * 4 + j][tx * 4];
#pragma unroll
            for (int jj = 0; jj < 4; ++jj) {
#pragma unroll
                for (int i = 0; i < 4; ++i) {
                    const float av = ((const float*)&a[i])[jj];
                    acc[i][0] = fmaf(av, bb[jj].x, acc[i][0]);
                    acc[i][1] = fmaf(av, bb[jj].y, acc[i][1]);
                    acc[i][2] = fmaf(av, bb[jj].z, acc[i][2]);
                    acc[i][3] = fmaf(av, bb[jj].w, acc[i][3]);
                }
            }
        }
        __syncthreads();
    }
#pragma unroll
    for (int i = 0; i < 4; ++i) {
        float4 o = make_float4(acc[i][0] * scale, acc[i][1] * scale,
                               acc[i][2] * scale, acc[i][3] * scale);
        *(float4*)&C[(size_t)(m0 + ty * 4 + i) * N + n0 + tx * 4] = o;
    }
}

// -------- per-batch L[m,e] = sum_k Mp[b,m,k] * Ep[b,e,k]  (A @ B^T) ------------
__global__ __launch_bounds__(256) void gemm_abt(const float* __restrict__ A,
                                                const float* __restrict__ B,
                                                float* __restrict__ C) {
    const int b = blockIdx.z;
    const float* Ab = A + (size_t)b * LEN_M * HDIM;
    const float* Bb = B + (size_t)b * LEN_E * HDIM;
    float* Cb = C + (size_t)b * LEN_M * LEN_E;

    __shared__ float As[TILE][LPAD];   // [m][kk]
    __shared__ float Bs[TILE][LPAD];   // [kk][e]  (transposed at staging)
    const int t  = threadIdx.x;
    const int tx = t & 15, ty = t >> 4;
    const int m0 = blockIdx.y * TILE, n0 = blockIdx.x * TILE;
    const int lm = t >> 4;
    const int lk = (t & 15) * 4;

    float acc[4][4] = {};

    for (int k0 = 0; k0 < HDIM; k0 += TILE) {
#pragma unroll
        for (int r = 0; r < 4; ++r) {
            const int row = lm + r * 16;
            *(float4*)&As[row][lk] = *(const float4*)&Ab[(size_t)(m0 + row) * HDIM + k0 + lk];
            const float4 vb = *(const float4*)&Bb[(size_t)(n0 + row) * HDIM + k0 + lk];
            Bs[lk + 0][row] = vb.x;   // transpose into [kk][e]
            Bs[lk + 1][row] = vb.y;
            Bs[lk + 2][row] = vb.z;
            Bs[lk + 3][row] = vb.w;
        }
        __syncthreads();
#pragma unroll
        for (int kk4 = 0; kk4 < 16; ++kk4) {
            float4 a[4], bb[4];
#pragma unroll
            for (int i = 0; i < 4; ++i) a[i]  = *(const float4*)&As[ty * 4 + i][kk4 * 4];
#pragma unroll
            for (int j = 0; j < 4; ++j) bb[j] = *(const float4*)&Bs[kk4 * 4 + j][tx * 4];
#pragma unroll
            for (int jj = 0; jj < 4; ++jj) {
#pragma unroll
                for (int i = 0; i < 4; ++i) {
                    const float av = ((const float*)&a[i])[jj];
                    acc[i][0] = fmaf(av, bb[jj].x, acc[i][0]);
                    acc[i][1] = fmaf(av, bb[jj].y, acc[i][1]);
                    acc[i][2] = fmaf(av, bb[jj].z, acc[i][2]);
                    acc[i][3] = fmaf(av, bb[jj].w, acc[i][3]);
                }
            }
        }
        __syncthreads();
    }
#pragma unroll
    for (int i = 0; i < 4; ++i) {
        float4 o = make_float4(acc[i][0], acc[i][1], acc[i][2], acc[i][3]);
        *(float4*)&Cb[(size_t)(m0 + ty * 4 + i) * LEN_E + n0 + tx * 4] = o;
    }
}

// ---------------- lambda gate: sigmoid([D|Cq|Cc] @ W_lambda + b) ---------------
__global__ __launch_bounds__(64) void lam_kernel(const float* __restrict__ D,
                                                 const float* __restrict__ Cq,
                                                 const float* __restrict__ Cc,
                                                 const float* __restrict__ Wl,
                                                 const float* __restrict__ bl,
                                                 float* __restrict__ lam) {
    const int bm   = blockIdx.x;       // 0..BSZ*LEN_M-1
    const int lane = threadIdx.x;      // 0..63
    const size_t base = (size_t)bm * HDIM;
    float s = 0.f;
    for (int h = lane; h < HDIM; h += 64) {
        s += D[base + h]  * Wl[h]
           + Cq[base + h] * Wl[HDIM + h]
           + Cc[base + h] * Wl[2 * HDIM + h];
    }
#pragma unroll
    for (int o = 32; o; o >>= 1) s += __shfl_xor(s, o);
    if (lane == 0) lam[bm] = 1.f / (1.f + expf(-(s + bl[0])));
}

// ------- dual softmax over e, gate-combine, scatter-add into vocab row ---------
__global__ __launch_bounds__(512) void softmax_scatter(const float* __restrict__ Lg,
                                                       const float* __restrict__ bq,
                                                       const float* __restrict__ bc,
                                                       const float* __restrict__ lam,
                                                       const int* __restrict__ idx,
                                                       float* __restrict__ out) {
    const int bm = blockIdx.x;         // 0..BSZ*LEN_M-1
    const int b  = bm >> 8;            // LEN_M = 256
    const int e  = threadIdx.x;        // 0..511

    const float L  = Lg[(size_t)bm * LEN_E + e];
    const float xq = L + bq[b * LEN_E + e];
    const float xc = L + bc[b * LEN_E + e];

    __shared__ float smq[8], smc[8], ssq[8], ssc[8];
    const int wid = e >> 6;

    // ---- block max (both softmaxes at once) ----
    float mq = xq, mc = xc;
#pragma unroll
    for (int o = 32; o; o >>= 1) {
        mq = fmaxf(mq, __shfl_xor(mq, o));
        mc = fmaxf(mc, __shfl_xor(mc, o));
    }
    if ((e & 63) == 0) { smq[wid] = mq; smc[wid] = mc; }
    __syncthreads();
    mq = smq[0]; mc = smc[0];
#pragma unroll
    for (int i = 1; i < 8; ++i) { mq = fmaxf(mq, smq[i]); mc = fmaxf(mc, smc[i]); }

    // ---- exp + block sum ----
    const float pq = expf(xq - mq);
    const float pc = expf(xc - mc);
    float sq = pq, sc = pc;
#pragma unroll
    for (int o = 32; o; o >>= 1) {
        sq += __shfl_xor(sq, o);
        sc += __shfl_xor(sc, o);
    }
    if ((e & 63) == 0) { ssq[wid] = sq; ssc[wid] = sc; }
    __syncthreads();
    sq = ssq[0]; sc = ssc[0];
#pragma unroll
    for (int i = 1; i < 8; ++i) { sq += ssq[i]; sc += ssc[i]; }

    const float lm_ = lam[bm];
    const float val = lm_ * (pq / sq) + (1.f - lm_) * (pc / sc);

    // scatter: row-private V-slice; atomics only resolve duplicate token ids
    atomicAdd(&out[(size_t)bm * VOCAB + idx[b * LEN_E + e]], val);
}

extern "C" void kernel_launch(void* const* d_in, const int* in_sizes, int n_in,
                              void* d_out, int out_size, void* d_ws, size_t ws_size,
                              hipStream_t stream) {
    const int*   idx = (const int*)  d_in[0];
    const float* D   = (const float*)d_in[1];
    const float* Cq  = (const float*)d_in[2];
    const float* Cc  = (const float*)d_in[3];
    const float* Mm  = (const float*)d_in[4];
    const float* E   = (const float*)d_in[5];
    const float* bq  = (const float*)d_in[6];
    const float* bc  = (const float*)d_in[7];
    const float* Wl  = (const float*)d_in[8];
    const float* bl  = (const float*)d_in[9];
    const float* We  = (const float*)d_in[10];
    const float* Wm  = (const float*)d_in[11];
    float* out = (float*)d_out;

    float* Ep  = (float*)d_ws;                          // BSZ*LEN_E*HDIM = 1,048,576 f
    float* Mp  = Ep + (size_t)BSZ * LEN_E * HDIM;       // BSZ*LEN_M*HDIM =   524,288 f
    float* Lg  = Mp + (size_t)BSZ * LEN_M * HDIM;       // BSZ*LEN_M*LEN_E =  524,288 f
    float* lam = Lg + (size_t)BSZ * LEN_M * LEN_E;      // BSZ*LEN_M       =     1,024 f

    hipMemsetAsync(d_out, 0, (size_t)out_size * sizeof(float), stream);

    // Ep = E @ W_e                     (2048 x 512 x 512)
    gemm_nn<<<dim3(HDIM / TILE, (BSZ * LEN_E) / TILE), 256, 0, stream>>>(
        E, We, Ep, BSZ * LEN_E, HDIM, HDIM, 1.0f);
    // Mp = (M @ W_m) * H^-0.5          (1024 x 512 x 512)
    gemm_nn<<<dim3(HDIM / TILE, (BSZ * LEN_M) / TILE), 256, 0, stream>>>(
        Mm, Wm, Mp, BSZ * LEN_M, HDIM, HDIM, 0.04419417382415922f);
    // lambda gate
    lam_kernel<<<BSZ * LEN_M, 64, 0, stream>>>(D, Cq, Cc, Wl, bl, lam);
    // logits = Mp @ Ep^T per batch     (4 x 256 x 512 x 512)
    gemm_abt<<<dim3(LEN_E / TILE, LEN_M / TILE, BSZ), 256, 0, stream>>>(Mp, Ep, Lg);
    // dual softmax + gate + scatter
    softmax_scatter<<<BSZ * LEN_M, LEN_E, 0, stream>>>(Lg, bq, bc, lam, idx, out);
}

// Round 2
// 102.340 us; speedup vs baseline: 1.2119x; 1.2119x over previous
//
#include <hip/hip_runtime.h>
#include <math.h>

#define BSZ 4
#define LEN_M 256
#define LEN_E 512
#define HDIM 512
#define VOCAB 32000

#define TILE 64
#define LPAD 68   // 64 + 4 pad: float4-aligned, row stride 272 words -> 2-way bank alias (free)

// ---------------- C[M,N] = scale * A[M,K] @ B[K,N], all row-major -------------
__global__ __launch_bounds__(256) void gemm_nn(const float* __restrict__ A,
                                               const float* __restrict__ B,
                                               float* __restrict__ C,
                                               int M, int N, int K, float scale) {
    __shared__ float As[TILE][LPAD];   // [m][kk]
    __shared__ float Bs[TILE][LPAD];   // [kk][n]
    const int t  = threadIdx.x;
    const int tx = t & 15, ty = t >> 4;
    const int m0 = blockIdx.y * TILE, n0 = blockIdx.x * TILE;
    const int lm = t >> 4;            // row within a 16-row staging pass
    const int lk = (t & 15) * 4;      // float4 column offset

    float acc[4][4] = {};

    for (int k0 = 0; k0 < K; k0 += TILE) {
#pragma unroll
        for (int r = 0; r < 4; ++r) {
            const int row = lm + r * 16;
            *(float4*)&As[row][lk] = *(const float4*)&A[(size_t)(m0 + row) * K + k0 + lk];
            *(float4*)&Bs[row][lk] = *(const float4*)&B[(size_t)(k0 + row) * N + n0 + lk];
        }
        __syncthreads();
#pragma unroll
        for (int kk4 = 0; kk4 < 16; ++kk4) {
            float4 a[4], bb[4];
#pragma unroll
            for (int i = 0; i < 4; ++i) a[i]  = *(const float4*)&As[ty * 4 + i][kk4 * 4];
#pragma unroll
            for (int j = 0; j < 4; ++j) bb[j] = *(const float4*)&Bs[kk4 * 4 + j][tx * 4];
#pragma unroll
            for (int jj = 0; jj < 4; ++jj) {
#pragma unroll
                for (int i = 0; i < 4; ++i) {
                    const float av = ((const float*)&a[i])[jj];
                    acc[i][0] = fmaf(av, bb[jj].x, acc[i][0]);
                    acc[i][1] = fmaf(av, bb[jj].y, acc[i][1]);
                    acc[i][2] = fmaf(av, bb[jj].z, acc[i][2]);
                    acc[i][3] = fmaf(av, bb[jj].w, acc[i][3]);
                }
            }
        }
        __syncthreads();
    }
#pragma unroll
    for (int i = 0; i < 4; ++i) {
        float4 o = make_float4(acc[i][0] * scale, acc[i][1] * scale,
                               acc[i][2] * scale, acc[i][3] * scale);
        *(float4*)&C[(size_t)(m0 + ty * 4 + i) * N + n0 + tx * 4] = o;
    }
}

// -------- per-batch L[m,e] = sum_k Mp[b,m,k] * Ep[b,e,k]  (A @ B^T) ------------
__global__ __launch_bounds__(256) void gemm_abt(const float* __restrict__ A,
                                                const float* __restrict__ B,
                                                float* __restrict__ C) {
    const int b = blockIdx.z;
    const float* Ab = A + (size_t)b * LEN_M * HDIM;
    const float* Bb = B + (size_t)b * LEN_E * HDIM;
    float* Cb = C + (size_t)b * LEN_M * LEN_E;

    __shared__ float As[TILE][LPAD];   // [m][kk]
    __shared__ float Bs[TILE][LPAD];   // [kk][e]  (transposed at staging)
    const int t  = threadIdx.x;
    const int tx = t & 15, ty = t >> 4;
    const int m0 = blockIdx.y * TILE, n0 = blockIdx.x * TILE;
    const int lm = t >> 4;
    const int lk = (t & 15) * 4;

    float acc[4][4] = {};

    for (int k0 = 0; k0 < HDIM; k0 += TILE) {
#pragma unroll
        for (int r = 0; r < 4; ++r) {
            const int row = lm + r * 16;
            *(float4*)&As[row][lk] = *(const float4*)&Ab[(size_t)(m0 + row) * HDIM + k0 + lk];
            const float4 vb = *(const float4*)&Bb[(size_t)(n0 + row) * HDIM + k0 + lk];
            Bs[lk + 0][row] = vb.x;   // transpose into [kk][e]
            Bs[lk + 1][row] = vb.y;
            Bs[lk + 2][row] = vb.z;
            Bs[lk + 3][row] = vb.w;
        }
        __syncthreads();
#pragma unroll
        for (int kk4 = 0; kk4 < 16; ++kk4) {
            float4 a[4], bb[4];
#pragma unroll
            for (int i = 0; i < 4; ++i) a[i]  = *(const float4*)&As[ty * 4 + i][kk4 * 4];
#pragma unroll
            for (int j = 0; j < 4; ++j) bb[j] = *(const float4*)&Bs[kk4 * 4 + j][tx * 4];
#pragma unroll
            for (int jj = 0; jj < 4; ++jj) {
#pragma unroll
                for (int i = 0; i < 4; ++i) {
                    const float av = ((const float*)&a[i])[jj];
                    acc[i][0] = fmaf(av, bb[jj].x, acc[i][0]);
                    acc[i][1] = fmaf(av, bb[jj].y, acc[i][1]);
                    acc[i][2] = fmaf(av, bb[jj].z, acc[i][2]);
                    acc[i][3] = fmaf(av, bb[jj].w, acc[i][3]);
                }
            }
        }
        __syncthreads();
    }
#pragma unroll
    for (int i = 0; i < 4; ++i) {
        float4 o = make_float4(acc[i][0], acc[i][1], acc[i][2], acc[i][3]);
        *(float4*)&Cb[(size_t)(m0 + ty * 4 + i) * LEN_E + n0 + tx * 4] = o;
    }
}

// ---------------- lambda gate: sigmoid([D|Cq|Cc] @ W_lambda + b) ---------------
__global__ __launch_bounds__(64) void lam_kernel(const float* __restrict__ D,
                                                 const float* __restrict__ Cq,
                                                 const float* __restrict__ Cc,
                                                 const float* __restrict__ Wl,
                                                 const float* __restrict__ bl,
                                                 float* __restrict__ lam) {
    const int bm   = blockIdx.x;       // 0..BSZ*LEN_M-1
    const int lane = threadIdx.x;      // 0..63
    const size_t base = (size_t)bm * HDIM;
    float s = 0.f;
    for (int h = lane; h < HDIM; h += 64) {
        s += D[base + h]  * Wl[h]
           + Cq[base + h] * Wl[HDIM + h]
           + Cc[base + h] * Wl[2 * HDIM + h];
    }
#pragma unroll
    for (int o = 32; o; o >>= 1) s += __shfl_xor(s, o);
    if (lane == 0) lam[bm] = 1.f / (1.f + expf(-(s + bl[0])));
}

// ------- dual softmax over e, gate-combine -> val[bm][e] -----------------------
__global__ __launch_bounds__(512) void softmax_val(const float* __restrict__ Lg,
                                                   const float* __restrict__ bq,
                                                   const float* __restrict__ bc,
                                                   const float* __restrict__ lam,
                                                   float* __restrict__ Val) {
    const int bm = blockIdx.x;         // 0..BSZ*LEN_M-1
    const int b  = bm >> 8;            // LEN_M = 256
    const int e  = threadIdx.x;        // 0..511

    const float L  = Lg[(size_t)bm * LEN_E + e];
    const float xq = L + bq[b * LEN_E + e];
    const float xc = L + bc[b * LEN_E + e];

    __shared__ float smq[8], smc[8], ssq[8], ssc[8];
    const int wid = e >> 6;

    // ---- block max (both softmaxes at once) ----
    float mq = xq, mc = xc;
#pragma unroll
    for (int o = 32; o; o >>= 1) {
        mq = fmaxf(mq, __shfl_xor(mq, o));
        mc = fmaxf(mc, __shfl_xor(mc, o));
    }
    if ((e & 63) == 0) { smq[wid] = mq; smc[wid] = mc; }
    __syncthreads();
    mq = smq[0]; mc = smc[0];
#pragma unroll
    for (int i = 1; i < 8; ++i) { mq = fmaxf(mq, smq[i]); mc = fmaxf(mc, smc[i]); }

    // ---- exp + block sum ----
    const float pq = expf(xq - mq);
    const float pc = expf(xc - mc);
    float sq = pq, sc = pc;
#pragma unroll
    for (int o = 32; o; o >>= 1) {
        sq += __shfl_xor(sq, o);
        sc += __shfl_xor(sc, o);
    }
    if ((e & 63) == 0) { ssq[wid] = sq; ssc[wid] = sc; }
    __syncthreads();
    sq = ssq[0]; sc = ssc[0];
#pragma unroll
    for (int i = 1; i < 8; ++i) { sq += ssq[i]; sc += ssc[i]; }

    const float lm_ = lam[bm];
    Val[(size_t)bm * LEN_E + e] = lm_ * (pq / sq) + (1.f - lm_) * (pc / sc);
}

// ------- zero + scatter + stream one vocab chunk of one row --------------------
#define CHUNK 8000          // 32000 / 4 chunks; 32 KB LDS -> ~5 blocks/CU
__global__ __launch_bounds__(256) void distribute(const float* __restrict__ Val,
                                                  const int* __restrict__ idx,
                                                  float* __restrict__ out) {
    __shared__ float buf[CHUNK];
    const int bm = blockIdx.x;          // row 0..1023
    const int c  = blockIdx.y;          // chunk 0..3
    const int b  = bm >> 8;
    const int t  = threadIdx.x;
    const int lo = c * CHUNK;

    // zero the LDS chunk (2000 float4)
#pragma unroll
    for (int i = t; i < CHUNK / 4; i += 256)
        ((float4*)buf)[i] = make_float4(0.f, 0.f, 0.f, 0.f);
    __syncthreads();

    // scatter the in-range entries (LDS atomics resolve duplicate token ids)
#pragma unroll
    for (int e = t; e < LEN_E; e += 256) {
        const int v = idx[b * LEN_E + e] - lo;
        if ((unsigned)v < (unsigned)CHUNK)
            atomicAdd(&buf[v], Val[(size_t)bm * LEN_E + e]);
    }
    __syncthreads();

    // stream the chunk to global (pure float4 stores, no global atomics)
    float4* __restrict__ dst = (float4*)(out + (size_t)bm * VOCAB + lo);
#pragma unroll
    for (int i = t; i < CHUNK / 4; i += 256)
        dst[i] = ((const float4*)buf)[i];
}

extern "C" void kernel_launch(void* const* d_in, const int* in_sizes, int n_in,
                              void* d_out, int out_size, void* d_ws, size_t ws_size,
                              hipStream_t stream) {
    const int*   idx = (const int*)  d_in[0];
    const float* D   = (const float*)d_in[1];
    const float* Cq  = (const float*)d_in[2];
    const float* Cc  = (const float*)d_in[3];
    const float* Mm  = (const float*)d_in[4];
    const float* E   = (const float*)d_in[5];
    const float* bq  = (const float*)d_in[6];
    const float* bc  = (const float*)d_in[7];
    const float* Wl  = (const float*)d_in[8];
    const float* bl  = (const float*)d_in[9];
    const float* We  = (const float*)d_in[10];
    const float* Wm  = (const float*)d_in[11];
    float* out = (float*)d_out;

    float* Ep  = (float*)d_ws;                          // BSZ*LEN_E*HDIM = 1,048,576 f
    float* Mp  = Ep + (size_t)BSZ * LEN_E * HDIM;       // BSZ*LEN_M*HDIM =   524,288 f
    float* Lg  = Mp + (size_t)BSZ * LEN_M * HDIM;       // BSZ*LEN_M*LEN_E =  524,288 f
    float* lam = Lg + (size_t)BSZ * LEN_M * LEN_E;      // BSZ*LEN_M       =     1,024 f
    float* Val = lam + BSZ * LEN_M;                     // BSZ*LEN_M*LEN_E =  524,288 f

    // Ep = E @ W_e                     (2048 x 512 x 512)
    gemm_nn<<<dim3(HDIM / TILE, (BSZ * LEN_E) / TILE), 256, 0, stream>>>(
        E, We, Ep, BSZ * LEN_E, HDIM, HDIM, 1.0f);
    // Mp = (M @ W_m) * H^-0.5          (1024 x 512 x 512)
    gemm_nn<<<dim3(HDIM / TILE, (BSZ * LEN_M) / TILE), 256, 0, stream>>>(
        Mm, Wm, Mp, BSZ * LEN_M, HDIM, HDIM, 0.04419417382415922f);
    // lambda gate
    lam_kernel<<<BSZ * LEN_M, 64, 0, stream>>>(D, Cq, Cc, Wl, bl, lam);
    // logits = Mp @ Ep^T per batch     (4 x 256 x 512 x 512)
    gemm_abt<<<dim3(LEN_E / TILE, LEN_M / TILE, BSZ), 256, 0, stream>>>(Mp, Ep, Lg);
    // dual softmax + gate -> Val
    softmax_val<<<BSZ * LEN_M, LEN_E, 0, stream>>>(Lg, bq, bc, lam, Val);
    // zero + scatter + stream (replaces hipMemsetAsync + global atomics)
    distribute<<<dim3(BSZ * LEN_M, VOCAB / CHUNK), 256, 0, stream>>>(Val, idx, out);
}

// Round 3
// 57.056 us; speedup vs baseline: 2.1738x; 1.7937x over previous
//
#include <hip/hip_runtime.h>
#include <math.h>

#define BSZ 4
#define LEN_M 256
#define LEN_E 512
#define HDIM 512
#define KDIM 512
#define VOCAB 32000

typedef __attribute__((ext_vector_type(8))) short bf16x8;
typedef __attribute__((ext_vector_type(4))) float f32x4;

__device__ inline ushort f2bf(float x) {
    union { float f; unsigned u; } v; v.f = x;
    unsigned r = v.u + 0x7FFFu + ((v.u >> 16) & 1u);   // RNE
    return (ushort)(r >> 16);
}

// ---- convert M, E, We, Wm (fp32) -> bf16 workspace, float4-granular ----------
// float4 counts: M 131072 | E 262144 | We 65536 | Wm 65536  (total 524288)
__global__ __launch_bounds__(256) void convert_bf16(const float* __restrict__ M_,
                                                    const float* __restrict__ E_,
                                                    const float* __restrict__ We_,
                                                    const float* __restrict__ Wm_,
                                                    ushort* __restrict__ Mbf,
                                                    ushort* __restrict__ Ebf,
                                                    ushort* __restrict__ Webf,
                                                    ushort* __restrict__ Wmbf) {
    const int i4 = blockIdx.x * 256 + threadIdx.x;
    const float* src; ushort* dst; int off;
    if      (i4 < 131072) { src = M_;  dst = Mbf;  off = 0; }
    else if (i4 < 393216) { src = E_;  dst = Ebf;  off = 131072; }
    else if (i4 < 458752) { src = We_; dst = Webf; off = 393216; }
    else                  { src = Wm_; dst = Wmbf; off = 458752; }
    const int j = i4 - off;
    const float4 v = ((const float4*)src)[j];
    ushort4 o; o.x = f2bf(v.x); o.y = f2bf(v.y); o.z = f2bf(v.z); o.w = f2bf(v.w);
    ((ushort4*)dst)[j] = o;
}

// ---- C[M][N] = scale * A[M][K] @ B[N][K]^T, bf16 in, fp32 or bf16 out --------
// 64x64 tile, 4 waves (2x2), each wave 32x32 = 2x2 frags of 16x16x32 MFMA.
// LDS rows padded to 72 bf16 (144 B): 16B-aligned ds_read_b128, 2-way bank alias.
#define LROW 72
template<bool OUT_BF16>
__global__ __launch_bounds__(256) void gemm_bt_mfma(const ushort* __restrict__ A,
                                                    const ushort* __restrict__ B,
                                                    void* __restrict__ C, int N,
                                                    long sA, long sB, long sC,
                                                    float scale) {
    __shared__ ushort As[64 * LROW];
    __shared__ ushort Bs[64 * LROW];
    const int t  = threadIdx.x;
    const int m0 = blockIdx.y * 64, n0 = blockIdx.x * 64;
    const size_t bz = blockIdx.z;
    const ushort* Ab = A + bz * (size_t)sA;
    const ushort* Bb = B + bz * (size_t)sB;

    const int wid = t >> 6, lane = t & 63;
    const int wr = wid >> 1, wc = wid & 1;
    const int lrow = lane & 15, lk = (lane >> 4) * 8;

    const int r0 = t >> 3;          // staging rows r0 and r0+32
    const int c8 = (t & 7) * 8;     // k-chunk (8 bf16 = 16 B)

    bf16x8 pa0, pa1, pb0, pb1;
    f32x4 acc[2][2] = {};

    // prologue: tile 0
    pa0 = *(const bf16x8*)&Ab[(size_t)(m0 + r0)      * KDIM + c8];
    pa1 = *(const bf16x8*)&Ab[(size_t)(m0 + r0 + 32) * KDIM + c8];
    pb0 = *(const bf16x8*)&Bb[(size_t)(n0 + r0)      * KDIM + c8];
    pb1 = *(const bf16x8*)&Bb[(size_t)(n0 + r0 + 32) * KDIM + c8];
    *(bf16x8*)&As[(r0)      * LROW + c8] = pa0;
    *(bf16x8*)&As[(r0 + 32) * LROW + c8] = pa1;
    *(bf16x8*)&Bs[(r0)      * LROW + c8] = pb0;
    *(bf16x8*)&Bs[(r0 + 32) * LROW + c8] = pb1;
    __syncthreads();

    for (int kt = 0; kt < KDIM / 64; ++kt) {
        if (kt + 1 < KDIM / 64) {           // prefetch next K-tile into regs
            const int k0 = (kt + 1) * 64;
            pa0 = *(const bf16x8*)&Ab[(size_t)(m0 + r0)      * KDIM + k0 + c8];
            pa1 = *(const bf16x8*)&Ab[(size_t)(m0 + r0 + 32) * KDIM + k0 + c8];
            pb0 = *(const bf16x8*)&Bb[(size_t)(n0 + r0)      * KDIM + k0 + c8];
            pb1 = *(const bf16x8*)&Bb[(size_t)(n0 + r0 + 32) * KDIM + k0 + c8];
        }
#pragma unroll
        for (int ks = 0; ks < 2; ++ks) {
            bf16x8 af[2], bfr[2];
#pragma unroll
            for (int i = 0; i < 2; ++i)
                af[i]  = *(const bf16x8*)&As[(wr * 32 + i * 16 + lrow) * LROW + ks * 32 + lk];
#pragma unroll
            for (int j = 0; j < 2; ++j)
                bfr[j] = *(const bf16x8*)&Bs[(wc * 32 + j * 16 + lrow) * LROW + ks * 32 + lk];
#pragma unroll
            for (int i = 0; i < 2; ++i)
#pragma unroll
                for (int j = 0; j < 2; ++j)
                    acc[i][j] = __builtin_amdgcn_mfma_f32_16x16x32_bf16(af[i], bfr[j], acc[i][j], 0, 0, 0);
        }
        __syncthreads();
        if (kt + 1 < KDIM / 64) {
            *(bf16x8*)&As[(r0)      * LROW + c8] = pa0;
            *(bf16x8*)&As[(r0 + 32) * LROW + c8] = pa1;
            *(bf16x8*)&Bs[(r0)      * LROW + c8] = pb0;
            *(bf16x8*)&Bs[(r0 + 32) * LROW + c8] = pb1;
            __syncthreads();
        }
    }

    // epilogue: C/D layout (m89): col = lane&15, row = (lane>>4)*4 + reg
    const int crow = m0 + wr * 32 + (lane >> 4) * 4;
    const int ccol = n0 + wc * 32 + lrow;
#pragma unroll
    for (int i = 0; i < 2; ++i)
#pragma unroll
        for (int j = 0; j < 2; ++j)
#pragma unroll
            for (int r = 0; r < 4; ++r) {
                const size_t o = bz * (size_t)sC + (size_t)(crow + i * 16 + r) * N + ccol + j * 16;
                const float v = acc[i][j][r] * scale;
                if (OUT_BF16) ((ushort*)C)[o] = f2bf(v);
                else          ((float*)C)[o]  = v;
            }
}

// ---- dual softmax over e + fused lambda gate -> Val[bm][e] -------------------
__global__ __launch_bounds__(512) void softmax_val(const float* __restrict__ Lg,
                                                   const float* __restrict__ bq,
                                                   const float* __restrict__ bc,
                                                   const float* __restrict__ D,
                                                   const float* __restrict__ Cq,
                                                   const float* __restrict__ Cc,
                                                   const float* __restrict__ Wl,
                                                   const float* __restrict__ bl,
                                                   float* __restrict__ Val) {
    const int bm = blockIdx.x;         // 0..BSZ*LEN_M-1
    const int b  = bm >> 8;            // LEN_M = 256
    const int e  = threadIdx.x;        // 0..511
    const int wid = e >> 6;

    __shared__ float sh[8], smq[8], smc[8], ssq[8], ssc[8];

    // ---- lambda: sigmoid([D|Cq|Cc] . W_lambda + b) ----
    const size_t rb = (size_t)bm * HDIM + e;
    float ls = D[rb] * Wl[e] + Cq[rb] * Wl[HDIM + e] + Cc[rb] * Wl[2 * HDIM + e];
#pragma unroll
    for (int o = 32; o; o >>= 1) ls += __shfl_xor(ls, o);
    if ((e & 63) == 0) sh[wid] = ls;

    const float L  = Lg[(size_t)bm * LEN_E + e];
    const float xq = L + bq[b * LEN_E + e];
    const float xc = L + bc[b * LEN_E + e];

    // ---- block max (both softmaxes at once) ----
    float mq = xq, mc = xc;
#pragma unroll
    for (int o = 32; o; o >>= 1) {
        mq = fmaxf(mq, __shfl_xor(mq, o));
        mc = fmaxf(mc, __shfl_xor(mc, o));
    }
    if ((e & 63) == 0) { smq[wid] = mq; smc[wid] = mc; }
    __syncthreads();
    float lsum = sh[0];
    mq = smq[0]; mc = smc[0];
#pragma unroll
    for (int i = 1; i < 8; ++i) {
        lsum += sh[i];
        mq = fmaxf(mq, smq[i]); mc = fmaxf(mc, smc[i]);
    }
    const float lam = 1.f / (1.f + expf(-(lsum + bl[0])));

    // ---- exp + block sum ----
    const float pq = expf(xq - mq);
    const float pc = expf(xc - mc);
    float sq = pq, sc = pc;
#pragma unroll
    for (int o = 32; o; o >>= 1) {
        sq += __shfl_xor(sq, o);
        sc += __shfl_xor(sc, o);
    }
    if ((e & 63) == 0) { ssq[wid] = sq; ssc[wid] = sc; }
    __syncthreads();
    sq = ssq[0]; sc = ssc[0];
#pragma unroll
    for (int i = 1; i < 8; ++i) { sq += ssq[i]; sc += ssc[i]; }

    Val[(size_t)bm * LEN_E + e] = lam * (pq / sq) + (1.f - lam) * (pc / sc);
}

// ---- zero + scatter + stream one vocab chunk of one row ----------------------
#define CHUNK 8000          // 32 KB LDS
__global__ __launch_bounds__(256) void distribute(const float* __restrict__ Val,
                                                  const int* __restrict__ idx,
                                                  float* __restrict__ out) {
    __shared__ float buf[CHUNK];
    const int bm = blockIdx.x;          // row 0..1023
    const int c  = blockIdx.y;          // chunk 0..3
    const int b  = bm >> 8;
    const int t  = threadIdx.x;
    const int lo = c * CHUNK;

    for (int i = t; i < CHUNK / 4; i += 256)
        ((float4*)buf)[i] = make_float4(0.f, 0.f, 0.f, 0.f);
    __syncthreads();

    for (int e = t; e < LEN_E; e += 256) {
        const int v = idx[b * LEN_E + e] - lo;
        if ((unsigned)v < (unsigned)CHUNK)
            atomicAdd(&buf[v], Val[(size_t)bm * LEN_E + e]);
    }
    __syncthreads();

    float4* __restrict__ dst = (float4*)(out + (size_t)bm * VOCAB + lo);
    for (int i = t; i < CHUNK / 4; i += 256)
        dst[i] = ((const float4*)buf)[i];
}

extern "C" void kernel_launch(void* const* d_in, const int* in_sizes, int n_in,
                              void* d_out, int out_size, void* d_ws, size_t ws_size,
                              hipStream_t stream) {
    const int*   idx = (const int*)  d_in[0];
    const float* D   = (const float*)d_in[1];
    const float* Cq  = (const float*)d_in[2];
    const float* Cc  = (const float*)d_in[3];
    const float* Mm  = (const float*)d_in[4];
    const float* E   = (const float*)d_in[5];
    const float* bq  = (const float*)d_in[6];
    const float* bc  = (const float*)d_in[7];
    const float* Wl  = (const float*)d_in[8];
    const float* bl  = (const float*)d_in[9];
    const float* We  = (const float*)d_in[10];
    const float* Wm  = (const float*)d_in[11];
    float* out = (float*)d_out;

    // workspace carve-up (16B aligned)
    char* w = (char*)d_ws;
    ushort* Mbf  = (ushort*)w;                 w += (size_t)1024 * 512 * 2;   // 1 MB
    ushort* Ebf  = (ushort*)w;                 w += (size_t)2048 * 512 * 2;   // 2 MB
    ushort* Webf = (ushort*)w;                 w += (size_t)512 * 512 * 2;
    ushort* Wmbf = (ushort*)w;                 w += (size_t)512 * 512 * 2;
    ushort* W2T  = (ushort*)w;                 w += (size_t)512 * 512 * 2;    // We @ Wm^T * s
    ushort* T1   = (ushort*)w;                 w += (size_t)1024 * 512 * 2;   // M @ W2T^T
    float*  Lg   = (float*)w;                  w += (size_t)1024 * 512 * 4;   // logits
    float*  Val  = (float*)w;                                                 // gated probs

    // 1) fp32 -> bf16
    convert_bf16<<<2048, 256, 0, stream>>>(Mm, E, We, Wm, Mbf, Ebf, Webf, Wmbf);
    // 2) W2T = (We @ Wm^T) * H^-0.5         [512 x 512], bf16 out
    gemm_bt_mfma<true><<<dim3(8, 8, 1), 256, 0, stream>>>(
        Webf, Wmbf, W2T, 512, 0, 0, 0, 0.04419417382415922f);
    // 3) T1 = M @ W2T^T                     [1024 x 512], bf16 out
    gemm_bt_mfma<true><<<dim3(8, 16, 1), 256, 0, stream>>>(
        Mbf, W2T, T1, 512, 0, 0, 0, 1.0f);
    // 4) logits[b] = T1[b] @ E[b]^T         [4 x 256 x 512], fp32 out
    gemm_bt_mfma<false><<<dim3(8, 4, BSZ), 256, 0, stream>>>(
        T1, Ebf, Lg, 512, 256 * 512, 512 * 512, 256 * 512, 1.0f);
    // 5) dual softmax + lambda -> Val
    softmax_val<<<BSZ * LEN_M, LEN_E, 0, stream>>>(Lg, bq, bc, D, Cq, Cc, Wl, bl, Val);
    // 6) zero + scatter + stream
    distribute<<<dim3(BSZ * LEN_M, VOCAB / CHUNK), 256, 0, stream>>>(Val, idx, out);
}